// Round 1
// baseline (241.338 us; speedup 1.0000x reference)
//
#include <hip/hip_runtime.h>

#define D_MODEL 128
#define HIDDEN 64
#define WPB 4  // waves per block

// Kernel 1: compute segment start offsets from sorted segment_ids.
// seg_start has B+1 entries; segment s spans [seg_start[s], seg_start[s+1]).
__global__ void seg_bounds_kernel(const int* __restrict__ seg, int n, int B,
                                  int* __restrict__ seg_start) {
  int i = blockIdx.x * blockDim.x + threadIdx.x;
  if (i >= n) return;
  int s = seg[i];
  if (i == 0) {
    for (int t = 0; t <= s; ++t) seg_start[t] = 0;
  } else {
    int p = seg[i - 1];
    for (int t = p + 1; t <= s; ++t) seg_start[t] = i;
  }
  if (i == n - 1) {
    for (int t = s + 1; t <= B; ++t) seg_start[t] = n;
  }
}

__device__ __forceinline__ float silu(float x) {
  return x / (1.0f + __expf(-x));
}

// Kernel 2: one wave64 per segment. Pool (mean over contiguous atom range)
// then 3-layer MLP. Per-wave LDS only; no block-wide barriers.
__global__ __launch_bounds__(256) void pool_mlp_kernel(
    const float* __restrict__ h, const int* __restrict__ seg_start,
    const float* __restrict__ W1, const float* __restrict__ b1,
    const float* __restrict__ W2, const float* __restrict__ b2,
    const float* __restrict__ W3, const float* __restrict__ b3,
    float* __restrict__ out, int B) {
  __shared__ float pooled_lds[WPB][D_MODEL];
  __shared__ float x1_lds[WPB][HIDDEN];

  const int wave = threadIdx.x >> 6;
  const int lane = threadIdx.x & 63;
  const int s = blockIdx.x * WPB + wave;
  if (s >= B) return;

  const int start = seg_start[s];
  const int end = seg_start[s + 1];
  const int cnt = end - start;

  // ---- pooling: lanes 0..31 cover the 128 floats (32 x float4) of even
  // atoms, lanes 32..63 the odd atoms -> 1KB per wave load instruction.
  const int half = lane >> 5;
  const int l32 = lane & 31;
  const float4* __restrict__ hv = reinterpret_cast<const float4*>(h);
  float4 acc = make_float4(0.f, 0.f, 0.f, 0.f);
  for (int a = start + half; a < end; a += 2) {
    float4 v = hv[a * 32 + l32];
    acc.x += v.x; acc.y += v.y; acc.z += v.z; acc.w += v.w;
  }
  // fold the two half-wave partials (both halves end with the full sum)
  acc.x += __shfl_xor(acc.x, 32);
  acc.y += __shfl_xor(acc.y, 32);
  acc.z += __shfl_xor(acc.z, 32);
  acc.w += __shfl_xor(acc.w, 32);

  const float inv = 1.0f / (float)max(cnt, 1);
  if (half == 0) {
    pooled_lds[wave][l32 * 4 + 0] = acc.x * inv;
    pooled_lds[wave][l32 * 4 + 1] = acc.y * inv;
    pooled_lds[wave][l32 * 4 + 2] = acc.z * inv;
    pooled_lds[wave][l32 * 4 + 3] = acc.w * inv;
  }
  __builtin_amdgcn_wave_barrier();  // ordering hint; wave64 is lockstep

  // ---- layer 1: lane j computes hidden unit j (broadcast LDS reads,
  // coalesced 256B weight-row loads; W1 is [128][64] row-major)
  float a1 = b1[lane];
#pragma unroll 8
  for (int k = 0; k < D_MODEL; ++k) {
    a1 = fmaf(pooled_lds[wave][k], W1[k * HIDDEN + lane], a1);
  }
  const float x1 = silu(a1);
  x1_lds[wave][lane] = x1;
  __builtin_amdgcn_wave_barrier();

  // ---- layer 2
  float a2 = b2[lane];
#pragma unroll 8
  for (int k = 0; k < HIDDEN; ++k) {
    a2 = fmaf(x1_lds[wave][k], W2[k * HIDDEN + lane], a2);
  }
  const float x2 = silu(a2);

  // ---- layer 3: dot(x2[64], W3[64]) via shuffle reduce
  float prod = x2 * W3[lane];
#pragma unroll
  for (int off = 32; off >= 1; off >>= 1) {
    prod += __shfl_xor(prod, off);
  }
  if (lane == 0) out[s] = prod + b3[0];
}

extern "C" void kernel_launch(void* const* d_in, const int* in_sizes, int n_in,
                              void* d_out, int out_size, void* d_ws, size_t ws_size,
                              hipStream_t stream) {
  const float* h = (const float*)d_in[0];
  const int* seg = (const int*)d_in[1];
  // d_in[2] = num_segments (device scalar; use out_size instead — host-known)
  const float* W1 = (const float*)d_in[3];
  const float* b1 = (const float*)d_in[4];
  const float* W2 = (const float*)d_in[5];
  const float* b2 = (const float*)d_in[6];
  const float* W3 = (const float*)d_in[7];
  const float* b3 = (const float*)d_in[8];
  float* out = (float*)d_out;

  const int n = in_sizes[1];      // number of atoms
  const int B = out_size;         // number of segments

  int* seg_start = (int*)d_ws;    // B+1 ints

  {
    int threads = 256;
    int blocks = (n + threads - 1) / threads;
    seg_bounds_kernel<<<blocks, threads, 0, stream>>>(seg, n, B, seg_start);
  }
  {
    int threads = 64 * WPB;
    int blocks = (B + WPB - 1) / WPB;
    pool_mlp_kernel<<<blocks, threads, 0, stream>>>(
        h, seg_start, W1, b1, W2, b2, W3, b3, out, B);
  }
}

// Round 2
// 217.157 us; speedup vs baseline: 1.1113x; 1.1113x over previous
//
#include <hip/hip_runtime.h>

#define D_MODEL 128
#define HIDDEN 64
#define WPB 8          // waves (= segments) per block
#define NTHREADS (WPB * 64)

// Kernel 1: compute segment start offsets from sorted segment_ids.
// seg_start has B+1 entries; segment s spans [seg_start[s], seg_start[s+1]).
__global__ void seg_bounds_kernel(const int* __restrict__ seg, int n, int B,
                                  int* __restrict__ seg_start) {
  int i = blockIdx.x * blockDim.x + threadIdx.x;
  if (i >= n) return;
  int s = seg[i];
  if (i == 0) {
    for (int t = 0; t <= s; ++t) seg_start[t] = 0;
  } else {
    int p = seg[i - 1];
    for (int t = p + 1; t <= s; ++t) seg_start[t] = i;
  }
  if (i == n - 1) {
    for (int t = s + 1; t <= B; ++t) seg_start[t] = n;
  }
}

__device__ __forceinline__ float silu(float x) {
  return x / (1.0f + __expf(-x));
}

// Kernel 2: one wave64 per segment; weights staged in LDS once per block.
__global__ __launch_bounds__(NTHREADS, 4) void pool_mlp_kernel(
    const float* __restrict__ h, const int* __restrict__ seg_start,
    const float* __restrict__ W1, const float* __restrict__ b1,
    const float* __restrict__ W2, const float* __restrict__ b2,
    const float* __restrict__ W3, const float* __restrict__ b3,
    float* __restrict__ out, int B) {
  __shared__ float sW1[D_MODEL * HIDDEN];  // 32 KB
  __shared__ float sW2[HIDDEN * HIDDEN];   // 16 KB
  __shared__ float sW3[HIDDEN];            // 256 B
  __shared__ float pooled_lds[WPB][D_MODEL];
  __shared__ float x1_lds[WPB][HIDDEN];

  const int tid = threadIdx.x;

  // ---- stage weights into LDS (coalesced float4), then one block barrier
  {
    const float4* __restrict__ w1v = reinterpret_cast<const float4*>(W1);
    float4* s1v = reinterpret_cast<float4*>(sW1);
#pragma unroll
    for (int i = tid; i < (D_MODEL * HIDDEN) / 4; i += NTHREADS) s1v[i] = w1v[i];
    const float4* __restrict__ w2v = reinterpret_cast<const float4*>(W2);
    float4* s2v = reinterpret_cast<float4*>(sW2);
#pragma unroll
    for (int i = tid; i < (HIDDEN * HIDDEN) / 4; i += NTHREADS) s2v[i] = w2v[i];
    if (tid < HIDDEN / 4) {
      reinterpret_cast<float4*>(sW3)[tid] =
          reinterpret_cast<const float4*>(W3)[tid];
    }
  }
  __syncthreads();  // all threads reach this before any per-segment exit

  const int wave = tid >> 6;
  const int lane = tid & 63;
  const int s = blockIdx.x * WPB + wave;
  if (s >= B) return;

  const int start = seg_start[s];
  const int end = seg_start[s + 1];
  const int cnt = end - start;

  // ---- pooling: lanes 0..31 cover even atoms (32 x float4 = one 512B row),
  // lanes 32..63 odd atoms -> 1KB per wave load instruction. 2x unrolled.
  const int half = lane >> 5;
  const int l32 = lane & 31;
  const float4* __restrict__ hv = reinterpret_cast<const float4*>(h);
  float4 acc0 = make_float4(0.f, 0.f, 0.f, 0.f);
  float4 acc1 = make_float4(0.f, 0.f, 0.f, 0.f);
  int a = start + half;
  for (; a + 2 < end; a += 4) {
    float4 v0 = hv[a * 32 + l32];
    float4 v1 = hv[(a + 2) * 32 + l32];
    acc0.x += v0.x; acc0.y += v0.y; acc0.z += v0.z; acc0.w += v0.w;
    acc1.x += v1.x; acc1.y += v1.y; acc1.z += v1.z; acc1.w += v1.w;
  }
  if (a < end) {
    float4 v0 = hv[a * 32 + l32];
    acc0.x += v0.x; acc0.y += v0.y; acc0.z += v0.z; acc0.w += v0.w;
  }
  acc0.x += acc1.x; acc0.y += acc1.y; acc0.z += acc1.z; acc0.w += acc1.w;
  // fold the two half-wave partials (both halves end with the full sum)
  acc0.x += __shfl_xor(acc0.x, 32);
  acc0.y += __shfl_xor(acc0.y, 32);
  acc0.z += __shfl_xor(acc0.z, 32);
  acc0.w += __shfl_xor(acc0.w, 32);

  const float inv = 1.0f / (float)max(cnt, 1);
  if (half == 0) {
    float4 p = make_float4(acc0.x * inv, acc0.y * inv, acc0.z * inv, acc0.w * inv);
    reinterpret_cast<float4*>(pooled_lds[wave])[l32] = p;
  }
  __builtin_amdgcn_wave_barrier();  // wave64 lockstep; LDS dep ordered by waitcnt

  // ---- layer 1: lane j computes hidden unit j (broadcast pooled reads,
  // lane-consecutive sW1 reads = conflict-free)
  float a1 = b1[lane];
#pragma unroll 8
  for (int k = 0; k < D_MODEL; ++k) {
    a1 = fmaf(pooled_lds[wave][k], sW1[k * HIDDEN + lane], a1);
  }
  const float x1 = silu(a1);
  x1_lds[wave][lane] = x1;
  __builtin_amdgcn_wave_barrier();

  // ---- layer 2
  float a2 = b2[lane];
#pragma unroll 8
  for (int k = 0; k < HIDDEN; ++k) {
    a2 = fmaf(x1_lds[wave][k], sW2[k * HIDDEN + lane], a2);
  }
  const float x2 = silu(a2);

  // ---- layer 3: dot(x2[64], W3[64]) via shuffle reduce
  float prod = x2 * sW3[lane];
#pragma unroll
  for (int off = 32; off >= 1; off >>= 1) {
    prod += __shfl_xor(prod, off);
  }
  if (lane == 0) out[s] = prod + b3[0];
}

extern "C" void kernel_launch(void* const* d_in, const int* in_sizes, int n_in,
                              void* d_out, int out_size, void* d_ws, size_t ws_size,
                              hipStream_t stream) {
  const float* h = (const float*)d_in[0];
  const int* seg = (const int*)d_in[1];
  // d_in[2] = num_segments (device scalar; use out_size instead — host-known)
  const float* W1 = (const float*)d_in[3];
  const float* b1 = (const float*)d_in[4];
  const float* W2 = (const float*)d_in[5];
  const float* b2 = (const float*)d_in[6];
  const float* W3 = (const float*)d_in[7];
  const float* b3 = (const float*)d_in[8];
  float* out = (float*)d_out;

  const int n = in_sizes[1];      // number of atoms
  const int B = out_size;         // number of segments

  int* seg_start = (int*)d_ws;    // B+1 ints

  {
    int threads = 256;
    int blocks = (n + threads - 1) / threads;
    seg_bounds_kernel<<<blocks, threads, 0, stream>>>(seg, n, B, seg_start);
  }
  {
    int blocks = (B + WPB - 1) / WPB;
    pool_mlp_kernel<<<blocks, NTHREADS, 0, stream>>>(
        h, seg_start, W1, b1, W2, b2, W3, b3, out, B);
  }
}

// Round 3
// 197.247 us; speedup vs baseline: 1.2235x; 1.1009x over previous
//
#include <hip/hip_runtime.h>

#define D_MODEL 128
#define HIDDEN 64
#define WPB 8                 // waves per block
#define NTHREADS (WPB * 64)
#define NBLOCKS 512           // persistent: ~2 blocks/CU on 256 CUs
#define W1_STRIDE 132         // 128 + 4 pad (float4-aligned, spreads banks)
#define W2_STRIDE 68          // 64 + 4 pad

// Kernel 1: segment start offsets from sorted segment_ids.
// seg_start has B+1 entries; segment s spans [seg_start[s], seg_start[s+1]).
__global__ void seg_bounds_kernel(const int* __restrict__ seg, int n, int B,
                                  int* __restrict__ seg_start) {
  int i = blockIdx.x * blockDim.x + threadIdx.x;
  if (i >= n) return;
  int s = seg[i];
  if (i == 0) {
    for (int t = 0; t <= s; ++t) seg_start[t] = 0;
  } else {
    int p = seg[i - 1];
    for (int t = p + 1; t <= s; ++t) seg_start[t] = i;
  }
  if (i == n - 1) {
    for (int t = s + 1; t <= B; ++t) seg_start[t] = n;
  }
}

__device__ __forceinline__ float silu(float x) {
  return x / (1.0f + __expf(-x));
}

// Kernel 2: persistent waves. Each wave owns a contiguous chunk of segments:
// pool (streaming float4, 1KB/wave-instr) then MLP from LDS-transposed
// weights (float4 reads). No block barriers after the one-time weight stage,
// so waves free-run and their pool/MLP phases interleave across the CU.
__global__ __launch_bounds__(NTHREADS, 4) void pool_mlp_kernel(
    const float* __restrict__ h, const int* __restrict__ seg_start,
    const float* __restrict__ W1, const float* __restrict__ b1,
    const float* __restrict__ W2, const float* __restrict__ b2,
    const float* __restrict__ W3, const float* __restrict__ b3,
    float* __restrict__ out, int B) {
  __shared__ float sW1T[HIDDEN * W1_STRIDE];  // W1^T padded: [j][k] 33.8 KB
  __shared__ float sW2T[HIDDEN * W2_STRIDE];  // W2^T padded: [j][k] 17.4 KB
  __shared__ float pooled_lds[WPB][D_MODEL];  // 4 KB
  __shared__ float x1_lds[WPB][HIDDEN];       // 2 KB

  const int tid = threadIdx.x;

  // ---- one-time staging: W1 (k,j) -> sW1T[j*W1_STRIDE + k], same for W2.
  // Global reads coalesced float4; LDS scatter is once-per-kernel cost.
#pragma unroll
  for (int i = tid; i < (D_MODEL * HIDDEN) / 4; i += NTHREADS) {
    float4 v = reinterpret_cast<const float4*>(W1)[i];
    int k = i >> 4;            // 16 float4 per k-row (HIDDEN=64)
    int j = (4 * i) & (HIDDEN - 1);
    sW1T[(j + 0) * W1_STRIDE + k] = v.x;
    sW1T[(j + 1) * W1_STRIDE + k] = v.y;
    sW1T[(j + 2) * W1_STRIDE + k] = v.z;
    sW1T[(j + 3) * W1_STRIDE + k] = v.w;
  }
#pragma unroll
  for (int i = tid; i < (HIDDEN * HIDDEN) / 4; i += NTHREADS) {
    float4 v = reinterpret_cast<const float4*>(W2)[i];
    int k = i >> 4;
    int j = (4 * i) & (HIDDEN - 1);
    sW2T[(j + 0) * W2_STRIDE + k] = v.x;
    sW2T[(j + 1) * W2_STRIDE + k] = v.y;
    sW2T[(j + 2) * W2_STRIDE + k] = v.z;
    sW2T[(j + 3) * W2_STRIDE + k] = v.w;
  }
  __syncthreads();  // only barrier in the kernel

  const int wave = tid >> 6;
  const int lane = tid & 63;

  // per-wave-constant params in registers (amortized over the chunk)
  const float b1l = b1[lane];
  const float b2l = b2[lane];
  const float w3l = W3[lane];
  const float b3l = b3[0];

  // ---- balanced contiguous chunk assignment
  const int G = gridDim.x * WPB;              // total waves
  const int g = blockIdx.x * WPB + wave;
  const int base = B / G;
  const int rem = B - base * G;
  const int my_cnt = base + (g < rem ? 1 : 0);
  const int my_s0 = g * base + (g < rem ? g : rem);
  if (my_cnt == 0) return;

  const int half = lane >> 5;
  const int l32 = lane & 63 & 31;
  const float4* __restrict__ hv = reinterpret_cast<const float4*>(h);
  const float4* __restrict__ pv =
      reinterpret_cast<const float4*>(&pooled_lds[wave][0]);
  const float4* __restrict__ x1v =
      reinterpret_cast<const float4*>(&x1_lds[wave][0]);
  const float4* __restrict__ w1v =
      reinterpret_cast<const float4*>(&sW1T[lane * W1_STRIDE]);
  const float4* __restrict__ w2v =
      reinterpret_cast<const float4*>(&sW2T[lane * W2_STRIDE]);

  int start = seg_start[my_s0];
  for (int si = 0; si < my_cnt; ++si) {
    const int s = my_s0 + si;
    const int end = seg_start[s + 1];
    const int cnt = end - start;

    // ---- pooling: lanes 0..31 = even atom's 128 floats, lanes 32..63 = odd
    // atom -> each wave instr loads 1KB contiguous. 2x unrolled.
    float4 acc0 = make_float4(0.f, 0.f, 0.f, 0.f);
    float4 acc1 = make_float4(0.f, 0.f, 0.f, 0.f);
    int a = start + half;
    for (; a + 2 < end; a += 4) {
      float4 v0 = hv[a * 32 + l32];
      float4 v1 = hv[(a + 2) * 32 + l32];
      acc0.x += v0.x; acc0.y += v0.y; acc0.z += v0.z; acc0.w += v0.w;
      acc1.x += v1.x; acc1.y += v1.y; acc1.z += v1.z; acc1.w += v1.w;
    }
    if (a < end) {
      float4 v0 = hv[a * 32 + l32];
      acc0.x += v0.x; acc0.y += v0.y; acc0.z += v0.z; acc0.w += v0.w;
    }
    acc0.x += acc1.x; acc0.y += acc1.y; acc0.z += acc1.z; acc0.w += acc1.w;
    acc0.x += __shfl_xor(acc0.x, 32);
    acc0.y += __shfl_xor(acc0.y, 32);
    acc0.z += __shfl_xor(acc0.z, 32);
    acc0.w += __shfl_xor(acc0.w, 32);

    const float inv = 1.0f / (float)max(cnt, 1);
    if (half == 0) {
      float4 p = make_float4(acc0.x * inv, acc0.y * inv,
                             acc0.z * inv, acc0.w * inv);
      reinterpret_cast<float4*>(&pooled_lds[wave][0])[l32] = p;
    }
    __builtin_amdgcn_wave_barrier();  // wave64 lockstep; waitcnt orders LDS

    // ---- layer 1: lane j = hidden unit j; broadcast pooled float4 +
    // contiguous W1^T row float4 (b128 reads, bank-phase optimal)
    float a1 = b1l;
#pragma unroll 8
    for (int t = 0; t < D_MODEL / 4; ++t) {
      float4 p = pv[t];
      float4 w = w1v[t];
      a1 = fmaf(p.x, w.x, a1);
      a1 = fmaf(p.y, w.y, a1);
      a1 = fmaf(p.z, w.z, a1);
      a1 = fmaf(p.w, w.w, a1);
    }
    const float x1 = silu(a1);
    x1_lds[wave][lane] = x1;
    __builtin_amdgcn_wave_barrier();

    // ---- layer 2
    float a2 = b2l;
#pragma unroll 8
    for (int t = 0; t < HIDDEN / 4; ++t) {
      float4 p = x1v[t];
      float4 w = w2v[t];
      a2 = fmaf(p.x, w.x, a2);
      a2 = fmaf(p.y, w.y, a2);
      a2 = fmaf(p.z, w.z, a2);
      a2 = fmaf(p.w, w.w, a2);
    }
    const float x2 = silu(a2);

    // ---- layer 3: dot(x2, W3) shuffle reduce
    float prod = x2 * w3l;
#pragma unroll
    for (int off = 32; off >= 1; off >>= 1) {
      prod += __shfl_xor(prod, off);
    }
    if (lane == 0) out[s] = prod + b3l;

    start = end;  // contiguous chunk: next segment starts where this ended
  }
}

extern "C" void kernel_launch(void* const* d_in, const int* in_sizes, int n_in,
                              void* d_out, int out_size, void* d_ws, size_t ws_size,
                              hipStream_t stream) {
  const float* h = (const float*)d_in[0];
  const int* seg = (const int*)d_in[1];
  // d_in[2] = num_segments (device scalar; use out_size instead — host-known)
  const float* W1 = (const float*)d_in[3];
  const float* b1 = (const float*)d_in[4];
  const float* W2 = (const float*)d_in[5];
  const float* b2 = (const float*)d_in[6];
  const float* W3 = (const float*)d_in[7];
  const float* b3 = (const float*)d_in[8];
  float* out = (float*)d_out;

  const int n = in_sizes[1];      // number of atoms
  const int B = out_size;         // number of segments

  int* seg_start = (int*)d_ws;    // B+1 ints

  {
    int threads = 256;
    int blocks = (n + threads - 1) / threads;
    seg_bounds_kernel<<<blocks, threads, 0, stream>>>(seg, n, B, seg_start);
  }
  {
    pool_mlp_kernel<<<NBLOCKS, NTHREADS, 0, stream>>>(
        h, seg_start, W1, b1, W2, b2, W3, b3, out, B);
  }
}